// Round 2
// baseline (407.539 us; speedup 1.0000x reference)
//
#include <hip/hip_runtime.h>
#include <hip/hip_bf16.h>

typedef unsigned short u16;
typedef __attribute__((ext_vector_type(4))) float f32x4;
typedef __attribute__((ext_vector_type(8))) short v8s;

#define NB 4
#define NT 8
#define NN 128
#define ND 512
#define NH 8
#define NDH 64
#define NS 1024

static __device__ __forceinline__ u16 f2b(float f) {
  __hip_bfloat16 h = __float2bfloat16(f);
  return *reinterpret_cast<u16*>(&h);
}
static __device__ __forceinline__ float b2f(u16 u) {
  __hip_bfloat16 h;
  *reinterpret_cast<u16*>(&h) = u;
  return __bfloat162float(h);
}

// ---------------- fp32 -> bf16 cast (vectorized, 8 elems/thread) ----------------
__global__ void __launch_bounds__(256) cast_kernel(const float* __restrict__ src,
                                                   u16* __restrict__ dst, int n8) {
  int i = blockIdx.x * blockDim.x + threadIdx.x;
  if (i >= n8) return;
  const float4* s4 = reinterpret_cast<const float4*>(src) + (size_t)i * 2;
  float4 a = s4[0], b = s4[1];
  u16 r[8] = {f2b(a.x), f2b(a.y), f2b(a.z), f2b(a.w),
              f2b(b.x), f2b(b.y), f2b(b.z), f2b(b.w)};
  *reinterpret_cast<v8s*>(dst + (size_t)i * 8) = *reinterpret_cast<v8s*>(r);
}

// ---------------- weight transpose + cast: W (K x N) f32 -> Wt (N x K) bf16 ------
__global__ void __launch_bounds__(256) transpose_cast_kernel(const float* __restrict__ W,
                                                             u16* __restrict__ Wt,
                                                             int K, int N) {
  __shared__ float t[32][33];
  int tx = threadIdx.x & 31, ty = threadIdx.x >> 5;
  int kb = blockIdx.y * 32, nb = blockIdx.x * 32;
#pragma unroll
  for (int i = 0; i < 4; i++) {
    int r = ty + i * 8;
    t[r][tx] = W[(size_t)(kb + r) * N + nb + tx];
  }
  __syncthreads();
#pragma unroll
  for (int i = 0; i < 4; i++) {
    int r = ty + i * 8;
    Wt[(size_t)(nb + r) * K + kb + tx] = f2b(t[tx][r]);
  }
}

// ---------------- extract coords (B,S,3) from x_0[..., :3] -----------------------
__global__ void coords_kernel(const float* __restrict__ x0, float* __restrict__ c, int n) {
  int i = blockIdx.x * blockDim.x + threadIdx.x;
  if (i < n) {
    c[i * 3 + 0] = x0[(size_t)i * ND + 0];
    c[i * 3 + 1] = x0[(size_t)i * ND + 1];
    c[i * 3 + 2] = x0[(size_t)i * ND + 2];
  }
}

// ---------------- bf16 MFMA GEMM, C = A(MxK) @ Wt(NxK)^T + bias ------------------
// mode 0: q-proj epilogue  -> RoPE, write (B,H,S,DH) bf16
// mode 1: kv-proj epilogue -> n<512: RoPE K -> (F,B,H,S,DH); n>=512: V -> (F,B,H,DH,S)
// mode 2: out-proj         -> +bo, write f32 d_out (B*S, 512)
__global__ void __launch_bounds__(256) gemm_kernel(const u16* __restrict__ A,
                                                   const u16* __restrict__ Wt,
                                                   const float* __restrict__ bias,
                                                   u16* __restrict__ outK,
                                                   u16* __restrict__ outV,
                                                   float* __restrict__ outF,
                                                   int M, int N, int K, int mode, int f) {
  __shared__ u16 At[64 * 40];
  __shared__ u16 Bt[64 * 40];
  int nt = N >> 6;
  int by = blockIdx.x / nt, bx = blockIdx.x % nt;
  int tid = threadIdx.x;
  int lane = tid & 63, wave = tid >> 6;
  int g = lane >> 4, li = lane & 15;
  int wm = (wave & 1) * 32, wn = (wave >> 1) * 32;
  f32x4 acc[2][2] = {};
  int sr = tid >> 2, sc = tid & 3;
  const u16* Arow = A + (size_t)(by * 64 + sr) * K + sc * 8;
  const u16* Brow = Wt + (size_t)(bx * 64 + sr) * K + sc * 8;
  for (int kb = 0; kb < K; kb += 32) {
    v8s av = *reinterpret_cast<const v8s*>(Arow + kb);
    v8s bv = *reinterpret_cast<const v8s*>(Brow + kb);
    __syncthreads();
    *reinterpret_cast<v8s*>(&At[sr * 40 + sc * 8]) = av;
    *reinterpret_cast<v8s*>(&Bt[sr * 40 + sc * 8]) = bv;
    __syncthreads();
#pragma unroll
    for (int mi = 0; mi < 2; mi++) {
      v8s a = *reinterpret_cast<v8s*>(&At[(wm + mi * 16 + li) * 40 + g * 8]);
#pragma unroll
      for (int ni = 0; ni < 2; ni++) {
        v8s b = *reinterpret_cast<v8s*>(&Bt[(wn + ni * 16 + li) * 40 + g * 8]);
        acc[mi][ni] = __builtin_amdgcn_mfma_f32_16x16x32_bf16(a, b, acc[mi][ni], 0, 0, 0);
      }
    }
  }
#pragma unroll
  for (int mi = 0; mi < 2; mi++)
#pragma unroll
    for (int ni = 0; ni < 2; ni++)
#pragma unroll
      for (int r = 0; r < 4; r++) {
        int mrow = by * 64 + wm + mi * 16 + 4 * g + r;
        int n = bx * 64 + wn + ni * 16 + li;
        float val = acc[mi][ni][r] + bias[n];
        if (mode == 2) {
          outF[(size_t)mrow * N + n] = val;
        } else {
          int b = mrow >> 10, s = mrow & 1023;
          bool isv = (mode == 1) && (n >= 512);
          float partner = __shfl_xor(val, 1);
          if (!isv) {
            int d = n & 63, h = (n & 511) >> 6;
            int j = d >> 1;
            float freq = __expf(-(float)j * 0.21586735246819178f);
            float ang = (float)(s >> 7) * freq;
            float sn, cs;
            sincosf(ang, &sn, &cs);
            float res = (n & 1) ? (partner * sn + val * cs) : (val * cs - partner * sn);
            size_t idx;
            if (mode == 0)
              idx = ((size_t)(b * NH + h) * NS + s) * NDH + d;
            else
              idx = ((size_t)((f * NB + b) * NH + h) * NS + s) * NDH + d;
            outK[idx] = f2b(res);
          } else {
            int vd = n - 512;
            int h = vd >> 6, d = vd & 63;
            outV[((size_t)((f * NB + b) * NH + h) * NDH + d) * NS + s] = f2b(val);
          }
        }
      }
}

// ---------------- SH-bias MLP 4->16->16->8, f32x4 LDS reads ----------------------
__global__ void __launch_bounds__(256) bias_kernel(const float* __restrict__ coords,
                                                   const float* __restrict__ W1,
                                                   const float* __restrict__ b1,
                                                   const float* __restrict__ W2,
                                                   const float* __restrict__ b2,
                                                   const float* __restrict__ W3,
                                                   const float* __restrict__ b3,
                                                   u16* __restrict__ biasT) {
  __shared__ float w[488];  // W1@0[64] b1@64 W2@80[256] b2@336 W3@352[128] b3@480
  int tid = threadIdx.x;
  if (tid < 64) w[tid] = W1[tid];
  if (tid < 16) { w[64 + tid] = b1[tid]; w[336 + tid] = b2[tid]; }
  w[80 + tid] = W2[tid];
  if (tid < 128) w[352 + tid] = W3[tid];
  if (tid < 8) w[480 + tid] = b3[tid];
  __syncthreads();
  int blk = blockIdx.x;
  int kb = blk & 3, q = (blk >> 2) & 1023, b = blk >> 12;
  int kk = kb * 256 + tid;
  float cqx = coords[(size_t)(b * NS + q) * 3 + 0];
  float cqy = coords[(size_t)(b * NS + q) * 3 + 1];
  float cqz = coords[(size_t)(b * NS + q) * 3 + 2];
  float rx = cqx - coords[(size_t)(b * NS + kk) * 3 + 0];
  float ry = cqy - coords[(size_t)(b * NS + kk) * 3 + 1];
  float rz = cqz - coords[(size_t)(b * NS + kk) * 3 + 2];
  float nrm = sqrtf(rx * rx + ry * ry + rz * rz);
  float inv = 1.0f / (nrm + 1e-6f);
  const float Y1 = 0.4886025119029199f;
  const float Y0 = 0.28209479177387814f;
  float shy = Y1 * ry * inv, shz = Y1 * rz * inv, shx = Y1 * rx * inv;
  const f32x4* W1v = reinterpret_cast<const f32x4*>(w);        // [4 rows][4 jv]
  const f32x4* b1v = reinterpret_cast<const f32x4*>(w + 64);   // [4]
  const f32x4* W2v = reinterpret_cast<const f32x4*>(w + 80);   // [16][4]
  const f32x4* b2v = reinterpret_cast<const f32x4*>(w + 336);  // [4]
  const f32x4* W3v = reinterpret_cast<const f32x4*>(w + 352);  // [16][2]
  const f32x4* b3v = reinterpret_cast<const f32x4*>(w + 480);  // [2]
  f32x4 h1v[4], h2v[4];
#pragma unroll
  for (int jv = 0; jv < 4; jv++) {
    f32x4 a = b1v[jv] + Y0 * W1v[jv] + shy * W1v[4 + jv] + shz * W1v[8 + jv] + shx * W1v[12 + jv];
#pragma unroll
    for (int c = 0; c < 4; c++) a[c] = a[c] / (1.0f + __expf(-a[c]));
    h1v[jv] = a;
  }
#pragma unroll
  for (int jv = 0; jv < 4; jv++) {
    f32x4 a = b2v[jv];
#pragma unroll
    for (int i = 0; i < 16; i++) a += h1v[i >> 2][i & 3] * W2v[i * 4 + jv];
#pragma unroll
    for (int c = 0; c < 4; c++) a[c] = a[c] / (1.0f + __expf(-a[c]));
    h2v[jv] = a;
  }
  f32x4 o0 = b3v[0], o1 = b3v[1];
#pragma unroll
  for (int i = 0; i < 16; i++) {
    float hs = h2v[i >> 2][i & 3];
    o0 += hs * W3v[i * 2];
    o1 += hs * W3v[i * 2 + 1];
  }
  size_t base = ((size_t)(b * NH) * NS + q) * NS + kk;
#pragma unroll
  for (int hh = 0; hh < 4; hh++) {
    biasT[base + (size_t)hh * NS * NS] = f2b(o0[hh]);
    biasT[base + (size_t)(hh + 4) * NS * NS] = f2b(o1[hh]);
  }
}

// ---------------- fused flash attention: 3 waves = 3 features, 16 q-rows ---------
// grid: B*H*(S/16) = 2048 blocks, 192 threads. XCD-clustered bh mapping.
__global__ void __launch_bounds__(192) attn_kernel(const u16* __restrict__ q,
                                                   const u16* __restrict__ kmat,
                                                   const u16* __restrict__ vt,
                                                   const u16* __restrict__ biasT,
                                                   const float* __restrict__ fw,
                                                   const float* __restrict__ denom,
                                                   u16* __restrict__ attno) {
  __shared__ u16 plds[3][2][512];   // per-wave double-buffered 16x32 P-tile
  __shared__ float comb[2][16][64]; // waves 1,2 partial outputs
  int d = blockIdx.x;
  int xcd = d & 7, idx = d >> 3;
  int bh = xcd + 8 * (idx >> 6);    // 4 bh per XCD -> K/V fits 4MB L2
  int qt = idx & 63;
  int h = bh & 7, b = bh >> 3;
  int wave = threadIdx.x >> 6;      // = feature index ff
  int lane = threadIdx.x & 63;
  int g = lane >> 4, li = lane & 15;
  int qw = qt * 16;
  int ff = wave;

  float f0 = fw[0], f1 = fw[1], f2v = fw[2];
  float mx = fmaxf(fmaxf(f0, f1), f2v);
  float e0 = __expf(f0 - mx), e1 = __expf(f1 - mx), e2 = __expf(f2v - mx);
  float gate = (ff == 0 ? e0 : (ff == 1 ? e1 : e2)) / (e0 + e1 + e2);
  float invd = 1.0f / denom[h];

  const u16* qbase = q + ((size_t)bh * NS + qw + li) * NDH + g * 8;
  v8s qa0 = *reinterpret_cast<const v8s*>(qbase);
  v8s qa1 = *reinterpret_cast<const v8s*>(qbase + 32);

  const u16* kbp = kmat + ((size_t)(ff * 32 + bh) * NS) * NDH;
  const u16* vbase = vt + ((size_t)(ff * 32 + bh) * NDH) * NS;
  const u16* bbase = biasT + ((size_t)bh * NS + qw + 4 * g) * NS;

  float m = 0.0f;                   // wave-uniform deferred max (T13)
  float lr[4] = {0.f, 0.f, 0.f, 0.f};
  f32x4 o[4] = {};
  f32x4 zero = {0.f, 0.f, 0.f, 0.f};

  for (int k0 = 0; k0 < NS; k0 += 32) {
    float bb[2][4];
#pragma unroll
    for (int kks = 0; kks < 2; kks++)
#pragma unroll
      for (int r = 0; r < 4; r++)
        bb[kks][r] = b2f(bbase[(size_t)r * NS + k0 + kks * 16 + li]);
    float pv[2][4];
#pragma unroll
    for (int kks = 0; kks < 2; kks++) {
      const u16* krow = kbp + (size_t)(k0 + kks * 16 + li) * NDH + g * 8;
      v8s kb0 = *reinterpret_cast<const v8s*>(krow);
      v8s kb1 = *reinterpret_cast<const v8s*>(krow + 32);
      f32x4 sc = __builtin_amdgcn_mfma_f32_16x16x32_bf16(qa0, kb0, zero, 0, 0, 0);
      sc = __builtin_amdgcn_mfma_f32_16x16x32_bf16(qa1, kb1, sc, 0, 0, 0);
#pragma unroll
      for (int r = 0; r < 4; r++) pv[kks][r] = sc[r] * invd + bb[kks][r];
    }
    // deferred-max check: per-lane max + wave ballot only (no shuffles)
    float pmax = pv[0][0];
#pragma unroll
    for (int kks = 0; kks < 2; kks++)
#pragma unroll
      for (int r = 0; r < 4; r++) pmax = fmaxf(pmax, pv[kks][r]);
    if (!__all(pmax - m <= 8.0f)) {  // rare slow path: raise m, rescale
      float rm = pmax;
      rm = fmaxf(rm, __shfl_xor(rm, 1));
      rm = fmaxf(rm, __shfl_xor(rm, 2));
      rm = fmaxf(rm, __shfl_xor(rm, 4));
      rm = fmaxf(rm, __shfl_xor(rm, 8));
      rm = fmaxf(rm, __shfl_xor(rm, 16));
      rm = fmaxf(rm, __shfl_xor(rm, 32));
      float sc2 = __expf(m - rm);
#pragma unroll
      for (int r = 0; r < 4; r++) lr[r] *= sc2;
#pragma unroll
      for (int ni = 0; ni < 4; ni++)
#pragma unroll
        for (int r = 0; r < 4; r++) o[ni][r] *= sc2;
      m = rm;
    }
    float p[2][4];
#pragma unroll
    for (int kks = 0; kks < 2; kks++)
#pragma unroll
      for (int r = 0; r < 4; r++) p[kks][r] = __expf(pv[kks][r] - m);
#pragma unroll
    for (int r = 0; r < 4; r++) lr[r] += p[0][r] + p[1][r];
    // P -> LDS transpose (double-buffered, XOR-swizzled 16B chunks)
    u16* pw = plds[wave][(k0 >> 5) & 1];
#pragma unroll
    for (int kks = 0; kks < 2; kks++)
#pragma unroll
      for (int r = 0; r < 4; r++) {
        int row = 4 * g + r, col = kks * 16 + li;
        int ch = (col >> 3) ^ ((row >> 2) & 3);
        pw[row * 32 + ch * 8 + (col & 7)] = f2b(p[kks][r]);
      }
    int chr = g ^ ((li >> 2) & 3);
    v8s pa = *reinterpret_cast<v8s*>(&pw[li * 32 + chr * 8]);
#pragma unroll
    for (int ni = 0; ni < 4; ni++) {
      v8s vb = *reinterpret_cast<const v8s*>(vbase + (size_t)(ni * 16 + li) * NS + k0 + g * 8);
      o[ni] = __builtin_amdgcn_mfma_f32_16x16x32_bf16(pa, vb, o[ni], 0, 0, 0);
    }
  }
  // row-sum reduce over the 16 li lanes (keys), then gate/l
  float scale[4];
#pragma unroll
  for (int r = 0; r < 4; r++) {
    float l = lr[r];
    l += __shfl_xor(l, 1);
    l += __shfl_xor(l, 2);
    l += __shfl_xor(l, 4);
    l += __shfl_xor(l, 8);
    scale[r] = gate / l;
  }
  if (wave > 0) {
#pragma unroll
    for (int ni = 0; ni < 4; ni++)
#pragma unroll
      for (int r = 0; r < 4; r++)
        comb[wave - 1][4 * g + r][ni * 16 + li] = o[ni][r] * scale[r];
  }
  __syncthreads();
  if (wave == 0) {
#pragma unroll
    for (int ni = 0; ni < 4; ni++)
#pragma unroll
      for (int r = 0; r < 4; r++) {
        float v = o[ni][r] * scale[r] + comb[0][4 * g + r][ni * 16 + li] +
                  comb[1][4 * g + r][ni * 16 + li];
        attno[((size_t)(b * NS + qw + 4 * g + r)) * ND + h * NDH + ni * 16 + li] = f2b(v);
      }
  }
}

extern "C" void kernel_launch(void* const* d_in, const int* in_sizes, int n_in,
                              void* d_out, int out_size, void* d_ws, size_t ws_size,
                              hipStream_t stream) {
  const float* x0 = (const float*)d_in[0];
  const float* v0 = (const float*)d_in[1];
  const float* cf = (const float*)d_in[2];
  const float* qd = (const float*)d_in[3];
  const float* Wq = (const float*)d_in[4];
  const float* bq = (const float*)d_in[5];
  const float* Wkv = (const float*)d_in[6];
  const float* bkv = (const float*)d_in[7];
  const float* Wo = (const float*)d_in[8];
  const float* bo = (const float*)d_in[9];
  const float* fw = (const float*)d_in[10];
  const float* dnm = (const float*)d_in[11];
  const float* W1 = (const float*)d_in[12];
  const float* b1 = (const float*)d_in[13];
  const float* W2 = (const float*)d_in[14];
  const float* b2 = (const float*)d_in[15];
  const float* W3 = (const float*)d_in[16];
  const float* b3 = (const float*)d_in[17];

  char* ws = (char*)d_ws;
  size_t off = 0;
  auto alloc = [&](size_t bytes) -> void* {
    void* p = ws + off;
    off = (off + bytes + 255) & ~(size_t)255;
    return p;
  };
  const size_t E = 4096ull * 512;
  u16* Aq = (u16*)alloc(E * 2);
  u16* Af = (u16*)alloc(3 * E * 2);
  u16* Wqt = (u16*)alloc(262144ull * 2);
  u16* Wkvt = (u16*)alloc(3ull * 524288 * 2);
  u16* Wot = (u16*)alloc(262144ull * 2);
  float* crd = (float*)alloc(4096ull * 3 * 4);
  u16* qr = (u16*)alloc(E * 2);
  u16* kr = (u16*)alloc(3 * E * 2);
  u16* vtr = (u16*)alloc(3 * E * 2);
  u16* biasT = (u16*)alloc(33554432ull * 2);
  u16* attno = (u16*)alloc(E * 2);
  (void)ws_size; (void)in_sizes; (void)n_in; (void)out_size;

  cast_kernel<<<1024, 256, 0, stream>>>(qd, Aq, 262144);
  cast_kernel<<<1024, 256, 0, stream>>>(x0, Af, 262144);
  cast_kernel<<<1024, 256, 0, stream>>>(v0, Af + E, 262144);
  cast_kernel<<<1024, 256, 0, stream>>>(cf, Af + 2 * E, 262144);
  coords_kernel<<<16, 256, 0, stream>>>(x0, crd, 4096);
  dim3 tg1(16, 16);
  transpose_cast_kernel<<<tg1, 256, 0, stream>>>(Wq, Wqt, 512, 512);
  dim3 tg2(32, 16);
  for (int f = 0; f < 3; f++)
    transpose_cast_kernel<<<tg2, 256, 0, stream>>>(Wkv + (size_t)f * 524288,
                                                   Wkvt + (size_t)f * 524288, 512, 1024);
  transpose_cast_kernel<<<tg1, 256, 0, stream>>>(Wo, Wot, 512, 512);

  gemm_kernel<<<512, 256, 0, stream>>>(Aq, Wqt, bq, qr, nullptr, nullptr,
                                       4096, 512, 512, 0, 0);
  for (int f = 0; f < 3; f++)
    gemm_kernel<<<1024, 256, 0, stream>>>(Af + (size_t)f * E, Wkvt + (size_t)f * 524288,
                                          bkv + f * 1024, kr, vtr, nullptr,
                                          4096, 1024, 512, 1, f);
  bias_kernel<<<16384, 256, 0, stream>>>(crd, W1, b1, W2, b2, W3, b3, biasT);
  attn_kernel<<<2048, 192, 0, stream>>>(qr, kr, vtr, biasT, fw, dnm, attno);
  gemm_kernel<<<512, 256, 0, stream>>>(attno, Wot, bo, nullptr, nullptr, (float*)d_out,
                                       4096, 512, 512, 2, 0);
}

// Round 3
// 396.000 us; speedup vs baseline: 1.0291x; 1.0291x over previous
//
#include <hip/hip_runtime.h>
#include <hip/hip_bf16.h>

typedef unsigned short u16;
typedef __attribute__((ext_vector_type(4))) float f32x4;
typedef __attribute__((ext_vector_type(8))) short v8s;

#define NB 4
#define NT 8
#define NN 128
#define ND 512
#define NH 8
#define NDH 64
#define NS 1024

static __device__ __forceinline__ u16 f2b(float f) {
  __hip_bfloat16 h = __float2bfloat16(f);
  return *reinterpret_cast<u16*>(&h);
}
static __device__ __forceinline__ float b2f(u16 u) {
  __hip_bfloat16 h;
  *reinterpret_cast<u16*>(&h) = u;
  return __bfloat162float(h);
}

// ---------------- fused fp32 -> bf16 cast for all 4 activation tensors -----------
__global__ void __launch_bounds__(256) cast4_kernel(const float* __restrict__ s0,
                                                    const float* __restrict__ s1,
                                                    const float* __restrict__ s2,
                                                    const float* __restrict__ s3,
                                                    u16* __restrict__ dst) {
  int blk = blockIdx.x;
  int seg = blk >> 10;                       // 1024 blocks per 2M-element tensor
  const float* src = seg == 0 ? s0 : (seg == 1 ? s1 : (seg == 2 ? s2 : s3));
  int i = (blk & 1023) * 256 + threadIdx.x;  // group-of-8 index
  const float4* s4 = reinterpret_cast<const float4*>(src) + (size_t)i * 2;
  float4 a = s4[0], b = s4[1];
  u16 r[8] = {f2b(a.x), f2b(a.y), f2b(a.z), f2b(a.w),
              f2b(b.x), f2b(b.y), f2b(b.z), f2b(b.w)};
  *reinterpret_cast<v8s*>(dst + (size_t)seg * 2097152 + (size_t)i * 8) =
      *reinterpret_cast<v8s*>(r);
}

// ---------------- weight transpose + cast: W (K x N) f32 -> Wt (N x K) bf16 ------
__global__ void __launch_bounds__(256) transpose_cast_kernel(const float* __restrict__ W,
                                                             u16* __restrict__ Wt,
                                                             int K, int N) {
  __shared__ float t[32][33];
  int tx = threadIdx.x & 31, ty = threadIdx.x >> 5;
  int kb = blockIdx.y * 32, nb = blockIdx.x * 32;
#pragma unroll
  for (int i = 0; i < 4; i++) {
    int r = ty + i * 8;
    t[r][tx] = W[(size_t)(kb + r) * N + nb + tx];
  }
  __syncthreads();
#pragma unroll
  for (int i = 0; i < 4; i++) {
    int r = ty + i * 8;
    Wt[(size_t)(nb + r) * K + kb + tx] = f2b(t[tx][r]);
  }
}

// ---------------- extract coords (B,S,3) from x_0[..., :3] -----------------------
__global__ void coords_kernel(const float* __restrict__ x0, float* __restrict__ c, int n) {
  int i = blockIdx.x * blockDim.x + threadIdx.x;
  if (i < n) {
    c[i * 3 + 0] = x0[(size_t)i * ND + 0];
    c[i * 3 + 1] = x0[(size_t)i * ND + 1];
    c[i * 3 + 2] = x0[(size_t)i * ND + 2];
  }
}

// ---------------- bf16 MFMA GEMM, C = A(MxK) @ Wt(NxK)^T + bias ------------------
__global__ void __launch_bounds__(256) gemm_kernel(const u16* __restrict__ A,
                                                   const u16* __restrict__ Wt,
                                                   const float* __restrict__ bias,
                                                   u16* __restrict__ outK,
                                                   u16* __restrict__ outV,
                                                   float* __restrict__ outF,
                                                   int M, int N, int K, int mode, int f) {
  __shared__ u16 At[64 * 40];
  __shared__ u16 Bt[64 * 40];
  int nt = N >> 6;
  int by = blockIdx.x / nt, bx = blockIdx.x % nt;
  int tid = threadIdx.x;
  int lane = tid & 63, wave = tid >> 6;
  int g = lane >> 4, li = lane & 15;
  int wm = (wave & 1) * 32, wn = (wave >> 1) * 32;
  f32x4 acc[2][2] = {};
  int sr = tid >> 2, sc = tid & 3;
  const u16* Arow = A + (size_t)(by * 64 + sr) * K + sc * 8;
  const u16* Brow = Wt + (size_t)(bx * 64 + sr) * K + sc * 8;
  for (int kb = 0; kb < K; kb += 32) {
    v8s av = *reinterpret_cast<const v8s*>(Arow + kb);
    v8s bv = *reinterpret_cast<const v8s*>(Brow + kb);
    __syncthreads();
    *reinterpret_cast<v8s*>(&At[sr * 40 + sc * 8]) = av;
    *reinterpret_cast<v8s*>(&Bt[sr * 40 + sc * 8]) = bv;
    __syncthreads();
#pragma unroll
    for (int mi = 0; mi < 2; mi++) {
      v8s a = *reinterpret_cast<v8s*>(&At[(wm + mi * 16 + li) * 40 + g * 8]);
#pragma unroll
      for (int ni = 0; ni < 2; ni++) {
        v8s b = *reinterpret_cast<v8s*>(&Bt[(wn + ni * 16 + li) * 40 + g * 8]);
        acc[mi][ni] = __builtin_amdgcn_mfma_f32_16x16x32_bf16(a, b, acc[mi][ni], 0, 0, 0);
      }
    }
  }
#pragma unroll
  for (int mi = 0; mi < 2; mi++)
#pragma unroll
    for (int ni = 0; ni < 2; ni++)
#pragma unroll
      for (int r = 0; r < 4; r++) {
        int mrow = by * 64 + wm + mi * 16 + 4 * g + r;
        int n = bx * 64 + wn + ni * 16 + li;
        float val = acc[mi][ni][r] + bias[n];
        if (mode == 2) {
          outF[(size_t)mrow * N + n] = val;
        } else {
          int b = mrow >> 10, s = mrow & 1023;
          bool isv = (mode == 1) && (n >= 512);
          float partner = __shfl_xor(val, 1);
          if (!isv) {
            int d = n & 63, h = (n & 511) >> 6;
            int j = d >> 1;
            float freq = __expf(-(float)j * 0.21586735246819178f);
            float ang = (float)(s >> 7) * freq;
            float sn, cs;
            sincosf(ang, &sn, &cs);
            float res = (n & 1) ? (partner * sn + val * cs) : (val * cs - partner * sn);
            size_t idx;
            if (mode == 0)
              idx = ((size_t)(b * NH + h) * NS + s) * NDH + d;
            else
              idx = ((size_t)((f * NB + b) * NH + h) * NS + s) * NDH + d;
            outK[idx] = f2b(res);
          } else {
            int vd = n - 512;
            int h = vd >> 6, d = vd & 63;
            outV[((size_t)((f * NB + b) * NH + h) * NDH + d) * NS + s] = f2b(val);
          }
        }
      }
}

// ---------------- SH-bias MLP 4->16->16->8, writes MFMA-fragment layout ----------
// slot(bh,q,k) = ((((bh*64+qt)*32+kt)*64 + g*16 + li)*8 + kks*4 + r
//   qt=q>>4, li=q&15, kt=k>>5, kks=(k>>4)&1, g=(k>>2)&3, r=k&3
__global__ void __launch_bounds__(256) bias_kernel(const float* __restrict__ coords,
                                                   const float* __restrict__ W1,
                                                   const float* __restrict__ b1,
                                                   const float* __restrict__ W2,
                                                   const float* __restrict__ b2,
                                                   const float* __restrict__ W3,
                                                   const float* __restrict__ b3,
                                                   u16* __restrict__ biasF) {
  __shared__ float w[488];
  int tid = threadIdx.x;
  if (tid < 64) w[tid] = W1[tid];
  if (tid < 16) { w[64 + tid] = b1[tid]; w[336 + tid] = b2[tid]; }
  w[80 + tid] = W2[tid];
  if (tid < 128) w[352 + tid] = W3[tid];
  if (tid < 8) w[480 + tid] = b3[tid];
  __syncthreads();
  int blk = blockIdx.x;
  int kb = blk & 3, q = (blk >> 2) & 1023, b = blk >> 12;
  int kk = kb * 256 + tid;
  float cqx = coords[(size_t)(b * NS + q) * 3 + 0];
  float cqy = coords[(size_t)(b * NS + q) * 3 + 1];
  float cqz = coords[(size_t)(b * NS + q) * 3 + 2];
  float rx = cqx - coords[(size_t)(b * NS + kk) * 3 + 0];
  float ry = cqy - coords[(size_t)(b * NS + kk) * 3 + 1];
  float rz = cqz - coords[(size_t)(b * NS + kk) * 3 + 2];
  float nrm = sqrtf(rx * rx + ry * ry + rz * rz);
  float inv = 1.0f / (nrm + 1e-6f);
  const float Y1 = 0.4886025119029199f;
  const float Y0 = 0.28209479177387814f;
  float shy = Y1 * ry * inv, shz = Y1 * rz * inv, shx = Y1 * rx * inv;
  const f32x4* W1v = reinterpret_cast<const f32x4*>(w);
  const f32x4* b1v = reinterpret_cast<const f32x4*>(w + 64);
  const f32x4* W2v = reinterpret_cast<const f32x4*>(w + 80);
  const f32x4* b2v = reinterpret_cast<const f32x4*>(w + 336);
  const f32x4* W3v = reinterpret_cast<const f32x4*>(w + 352);
  const f32x4* b3v = reinterpret_cast<const f32x4*>(w + 480);
  f32x4 h1v[4], h2v[4];
#pragma unroll
  for (int jv = 0; jv < 4; jv++) {
    f32x4 a = b1v[jv] + Y0 * W1v[jv] + shy * W1v[4 + jv] + shz * W1v[8 + jv] + shx * W1v[12 + jv];
#pragma unroll
    for (int c = 0; c < 4; c++) a[c] = a[c] / (1.0f + __expf(-a[c]));
    h1v[jv] = a;
  }
#pragma unroll
  for (int jv = 0; jv < 4; jv++) {
    f32x4 a = b2v[jv];
#pragma unroll
    for (int i = 0; i < 16; i++) a += h1v[i >> 2][i & 3] * W2v[i * 4 + jv];
#pragma unroll
    for (int c = 0; c < 4; c++) a[c] = a[c] / (1.0f + __expf(-a[c]));
    h2v[jv] = a;
  }
  f32x4 o0 = b3v[0], o1 = b3v[1];
#pragma unroll
  for (int i = 0; i < 16; i++) {
    float hs = h2v[i >> 2][i & 3];
    o0 += hs * W3v[i * 2];
    o1 += hs * W3v[i * 2 + 1];
  }
  int qt = q >> 4, liq = q & 15;
  int kt = kk >> 5, kks = (kk >> 4) & 1, gg = (kk >> 2) & 3, rr = kk & 3;
  const size_t hstride = 1048576;  // 64*32*64*8 u16 per (b,h) plane
  size_t slot0 = ((((size_t)(b * NH) * 64 + qt) * 32 + kt) * 64 + gg * 16 + liq) * 8 +
                 kks * 4 + rr;
#pragma unroll
  for (int hh = 0; hh < 4; hh++) {
    biasF[slot0 + (size_t)hh * hstride] = f2b(o0[hh]);
    biasF[slot0 + (size_t)(hh + 4) * hstride] = f2b(o1[hh]);
  }
}

// ---------------- fused flash attention: swapped QK^T, store-free inner loop -----
// block = 128 thr = 2 waves (split-K halves); each wave: 16 q-rows x 512 keys x 3 feats.
__global__ void __launch_bounds__(128, 3) attn_kernel(const u16* __restrict__ q,
                                                      const u16* __restrict__ kmat,
                                                      const u16* __restrict__ vt,
                                                      const u16* __restrict__ biasF,
                                                      const float* __restrict__ fw,
                                                      const float* __restrict__ denom,
                                                      u16* __restrict__ attno) {
  __shared__ float comb_o[3][16][65];  // +1 pad: conflict-free epilogue reads
  __shared__ float comb_l[3][16];
  __shared__ float comb_m[3];
  int d = blockIdx.x;
  int xcd = d & 7, idx = d >> 3;
  int bh = xcd + 8 * (idx >> 6);  // 4 bh per XCD -> K/V+bias stream L2 locality
  int qt = idx & 63;
  int h = bh & 7, b = bh >> 3;
  int wave = threadIdx.x >> 6;
  int lane = threadIdx.x & 63;
  int g = lane >> 4, li = lane & 15;

  float f0 = fw[0], f1 = fw[1], f2v = fw[2];
  float mxg = fmaxf(fmaxf(f0, f1), f2v);
  float e0 = __expf(f0 - mxg), e1 = __expf(f1 - mxg), e2 = __expf(f2v - mxg);
  float es = e0 + e1 + e2;
  float gates[3] = {e0 / es, e1 / es, e2 / es};
  float invd = 1.0f / denom[h];

  // Q as B-fragment: lane holds Q[q = qt*16+li][d = g*8..g*8+7 (+32)]
  const u16* qbase = q + ((size_t)bh * NS + qt * 16 + li) * NDH + g * 8;
  v8s qa0 = *reinterpret_cast<const v8s*>(qbase);
  v8s qa1 = *reinterpret_cast<const v8s*>(qbase + 32);

  const u16* bfrag = biasF + (size_t)bh * 1048576 + (size_t)qt * 16384;

  float m[3] = {0.f, 0.f, 0.f};   // wave-uniform deferred max per feature
  float lr[3] = {0.f, 0.f, 0.f};  // per-lane partial row-sum (q = li)
  f32x4 o[3][4] = {};
  f32x4 zero = {0.f, 0.f, 0.f, 0.f};

  int s0lane = ((g & 1) << 5) + li;  // repack source lane 0 (gs=2*(g&1))
  int kksT = g >> 1;                 // which kks half this lane consumes

  for (int t = 0; t < 16; t++) {
    int kt = wave * 16 + t;
    int k0 = kt * 32;
    // bias fragment: ONE 16B load per lane per tile
    v8s bb = *reinterpret_cast<const v8s*>(bfrag + ((size_t)kt * 64 + lane) * 8);
    // K fragments, all 3 features (A-fragment: lane holds K[k0+kks*16+li][d])
    v8s kf[3][2][2];
#pragma unroll
    for (int ff = 0; ff < 3; ff++) {
      const u16* kbp = kmat + ((size_t)(ff * 32 + bh) * NS) * NDH;
#pragma unroll
      for (int kks = 0; kks < 2; kks++) {
        const u16* krow = kbp + (size_t)(k0 + kks * 16 + li) * NDH + g * 8;
        kf[ff][kks][0] = *reinterpret_cast<const v8s*>(krow);
        kf[ff][kks][1] = *reinterpret_cast<const v8s*>(krow + 32);
      }
    }
#pragma unroll
    for (int ff = 0; ff < 3; ff++) {
      const u16* vbase = vt + ((size_t)(ff * 32 + bh) * NDH) * NS;
      v8s vb[4];
#pragma unroll
      for (int ni = 0; ni < 4; ni++)
        vb[ni] = *reinterpret_cast<const v8s*>(vbase + (size_t)(ni * 16 + li) * NS + k0 + g * 8);
      // swapped QK^T: C lane holds P[k = k0+kks*16+4g+r][q = li]
      float pv[2][4];
#pragma unroll
      for (int kks = 0; kks < 2; kks++) {
        f32x4 sc = __builtin_amdgcn_mfma_f32_16x16x32_bf16(kf[ff][kks][0], qa0, zero, 0, 0, 0);
        sc = __builtin_amdgcn_mfma_f32_16x16x32_bf16(kf[ff][kks][1], qa1, sc, 0, 0, 0);
#pragma unroll
        for (int r = 0; r < 4; r++)
          pv[kks][r] = sc[r] * invd + b2f((u16)bb[kks * 4 + r]);
      }
      float pmax = pv[0][0];
#pragma unroll
      for (int kks = 0; kks < 2; kks++)
#pragma unroll
        for (int r = 0; r < 4; r++) pmax = fmaxf(pmax, pv[kks][r]);
      if (!__all(pmax - m[ff] <= 8.0f)) {  // rare: raise wave-uniform max, rescale
        float rm = pmax;
        rm = fmaxf(rm, __shfl_xor(rm, 1));
        rm = fmaxf(rm, __shfl_xor(rm, 2));
        rm = fmaxf(rm, __shfl_xor(rm, 4));
        rm = fmaxf(rm, __shfl_xor(rm, 8));
        rm = fmaxf(rm, __shfl_xor(rm, 16));
        rm = fmaxf(rm, __shfl_xor(rm, 32));
        float sc2 = __expf(m[ff] - rm);
        lr[ff] *= sc2;
#pragma unroll
        for (int ni = 0; ni < 4; ni++)
#pragma unroll
          for (int r = 0; r < 4; r++) o[ff][ni][r] *= sc2;
        m[ff] = rm;
      }
      float p[2][4];
#pragma unroll
      for (int kks = 0; kks < 2; kks++)
#pragma unroll
        for (int r = 0; r < 4; r++) {
          p[kks][r] = __expf(pv[kks][r] - m[ff]);
          lr[ff] += p[kks][r];
        }
      // in-register P repack: (gs,li) psrc[kks][j] -> (gt=2*kks+(gs>>1), li) w[2*(gs&1)+j]
      unsigned int ps00 = ((unsigned int)f2b(p[0][1]) << 16) | f2b(p[0][0]);
      unsigned int ps01 = ((unsigned int)f2b(p[0][3]) << 16) | f2b(p[0][2]);
      unsigned int ps10 = ((unsigned int)f2b(p[1][1]) << 16) | f2b(p[1][0]);
      unsigned int ps11 = ((unsigned int)f2b(p[1][3]) << 16) | f2b(p[1][2]);
      int a00 = __shfl((int)ps00, s0lane), a01 = __shfl((int)ps01, s0lane);
      int a10 = __shfl((int)ps10, s0lane), a11 = __shfl((int)ps11, s0lane);
      int c00 = __shfl((int)ps00, s0lane + 16), c01 = __shfl((int)ps01, s0lane + 16);
      int c10 = __shfl((int)ps10, s0lane + 16), c11 = __shfl((int)ps11, s0lane + 16);
      int warr[4];
      warr[0] = kksT ? a10 : a00;
      warr[1] = kksT ? a11 : a01;
      warr[2] = kksT ? c10 : c00;
      warr[3] = kksT ? c11 : c01;
      v8s pa = *reinterpret_cast<v8s*>(warr);
#pragma unroll
      for (int ni = 0; ni < 4; ni++)
        o[ff][ni] = __builtin_amdgcn_mfma_f32_16x16x32_bf16(pa, vb[ni], o[ff][ni], 0, 0, 0);
    }
  }
  // reduce l across g-groups: lane then holds full l for q = li
#pragma unroll
  for (int ff = 0; ff < 3; ff++) {
    lr[ff] += __shfl_xor(lr[ff], 16);
    lr[ff] += __shfl_xor(lr[ff], 32);
  }
  if (wave == 1) {
#pragma unroll
    for (int ff = 0; ff < 3; ff++) {
      if (g == 0) comb_l[ff][li] = lr[ff];
      if (lane == 0) comb_m[ff] = m[ff];
#pragma unroll
      for (int ni = 0; ni < 4; ni++)
#pragma unroll
        for (int r = 0; r < 4; r++)
          comb_o[ff][4 * g + r][ni * 16 + li] = o[ff][ni][r];
    }
  }
  __syncthreads();
  if (wave == 0) {
    float out[4][4] = {};
#pragma unroll
    for (int ff = 0; ff < 3; ff++) {
      float m1 = comb_m[ff];
      float M = fmaxf(m[ff], m1);
      float sA = __expf(m[ff] - M), sB = __expf(m1 - M);
      float lt = lr[ff] * sA + comb_l[ff][li] * sB;
      float scl = gates[ff] / lt;
      float srow[4];
#pragma unroll
      for (int r = 0; r < 4; r++)
        srow[r] = __shfl(scl, (lane & 48) | (((lane >> 2) & 12) + r));
#pragma unroll
      for (int ni = 0; ni < 4; ni++)
#pragma unroll
        for (int r = 0; r < 4; r++)
          out[ni][r] += (o[ff][ni][r] * sA + comb_o[ff][4 * g + r][ni * 16 + li] * sB) * srow[r];
    }
#pragma unroll
    for (int ni = 0; ni < 4; ni++)
#pragma unroll
      for (int r = 0; r < 4; r++)
        attno[((size_t)(b * NS + qt * 16 + 4 * g + r)) * ND + h * NDH + ni * 16 + li] =
            f2b(out[ni][r]);
  }
}

extern "C" void kernel_launch(void* const* d_in, const int* in_sizes, int n_in,
                              void* d_out, int out_size, void* d_ws, size_t ws_size,
                              hipStream_t stream) {
  const float* x0 = (const float*)d_in[0];
  const float* v0 = (const float*)d_in[1];
  const float* cf = (const float*)d_in[2];
  const float* qd = (const float*)d_in[3];
  const float* Wq = (const float*)d_in[4];
  const float* bq = (const float*)d_in[5];
  const float* Wkv = (const float*)d_in[6];
  const float* bkv = (const float*)d_in[7];
  const float* Wo = (const float*)d_in[8];
  const float* bo = (const float*)d_in[9];
  const float* fw = (const float*)d_in[10];
  const float* dnm = (const float*)d_in[11];
  const float* W1 = (const float*)d_in[12];
  const float* b1 = (const float*)d_in[13];
  const float* W2 = (const float*)d_in[14];
  const float* b2 = (const float*)d_in[15];
  const float* W3 = (const float*)d_in[16];
  const float* b3 = (const float*)d_in[17];

  char* ws = (char*)d_ws;
  size_t off = 0;
  auto alloc = [&](size_t bytes) -> void* {
    void* p = ws + off;
    off = (off + bytes + 255) & ~(size_t)255;
    return p;
  };
  const size_t E = 4096ull * 512;
  u16* Aq = (u16*)alloc(E * 2);
  u16* Af = (u16*)alloc(3 * E * 2);  // contiguous after Aq (cast4 relies on this)
  u16* Wqt = (u16*)alloc(262144ull * 2);
  u16* Wkvt = (u16*)alloc(3ull * 524288 * 2);
  u16* Wot = (u16*)alloc(262144ull * 2);
  float* crd = (float*)alloc(4096ull * 3 * 4);
  u16* qr = (u16*)alloc(E * 2);
  u16* kr = (u16*)alloc(3 * E * 2);
  u16* vtr = (u16*)alloc(3 * E * 2);
  u16* biasF = (u16*)alloc(33554432ull * 2);
  u16* attno = (u16*)alloc(E * 2);
  (void)ws_size; (void)in_sizes; (void)n_in; (void)out_size; (void)Af;

  cast4_kernel<<<4096, 256, 0, stream>>>(qd, x0, v0, cf, Aq);
  coords_kernel<<<16, 256, 0, stream>>>(x0, crd, 4096);
  dim3 tg1(16, 16);
  transpose_cast_kernel<<<tg1, 256, 0, stream>>>(Wq, Wqt, 512, 512);
  dim3 tg2(32, 16);
  for (int f = 0; f < 3; f++)
    transpose_cast_kernel<<<tg2, 256, 0, stream>>>(Wkv + (size_t)f * 524288,
                                                   Wkvt + (size_t)f * 524288, 512, 1024);
  transpose_cast_kernel<<<tg1, 256, 0, stream>>>(Wo, Wot, 512, 512);

  gemm_kernel<<<512, 256, 0, stream>>>(Aq, Wqt, bq, qr, nullptr, nullptr,
                                       4096, 512, 512, 0, 0);
  for (int f = 0; f < 3; f++)
    gemm_kernel<<<1024, 256, 0, stream>>>(Af + (size_t)f * E, Wkvt + (size_t)f * 524288,
                                          bkv + f * 1024, kr, vtr, nullptr,
                                          4096, 1024, 512, 1, f);
  bias_kernel<<<16384, 256, 0, stream>>>(crd, W1, b1, W2, b2, W3, b3, biasF);
  attn_kernel<<<2048, 128, 0, stream>>>(qr, kr, vtr, biasF, fw, dnm, attno);
  gemm_kernel<<<512, 256, 0, stream>>>(attno, Wot, bo, nullptr, nullptr, (float*)d_out,
                                       4096, 512, 512, 2, 0);
}

// Round 4
// 275.606 us; speedup vs baseline: 1.4787x; 1.4368x over previous
//
#include <hip/hip_runtime.h>
#include <hip/hip_bf16.h>

typedef unsigned short u16;
typedef __attribute__((ext_vector_type(4))) float f32x4;
typedef __attribute__((ext_vector_type(8))) short v8s;

#define NB 4
#define NT 8
#define NN 128
#define ND 512
#define NH 8
#define NDH 64
#define NS 1024

static __device__ __forceinline__ u16 f2b(float f) {
  __hip_bfloat16 h = __float2bfloat16(f);
  return *reinterpret_cast<u16*>(&h);
}
static __device__ __forceinline__ float b2f(u16 u) {
  __hip_bfloat16 h;
  *reinterpret_cast<u16*>(&h) = u;
  return __bfloat162float(h);
}
// async global->LDS, 16B per lane (dest must be wave-linear: base + lane*16)
static __device__ __forceinline__ void gl16(const u16* g, u16* l) {
  __builtin_amdgcn_global_load_lds(
      (const __attribute__((address_space(1))) unsigned int*)g,
      (__attribute__((address_space(3))) unsigned int*)l, 16, 0, 0);
}

// ---------------- fused fp32 -> bf16 cast for all 4 activation tensors -----------
__global__ void __launch_bounds__(256) cast4_kernel(const float* __restrict__ s0,
                                                    const float* __restrict__ s1,
                                                    const float* __restrict__ s2,
                                                    const float* __restrict__ s3,
                                                    u16* __restrict__ dst) {
  int blk = blockIdx.x;
  int seg = blk >> 10;
  const float* src = seg == 0 ? s0 : (seg == 1 ? s1 : (seg == 2 ? s2 : s3));
  int i = (blk & 1023) * 256 + threadIdx.x;
  const float4* s4 = reinterpret_cast<const float4*>(src) + (size_t)i * 2;
  float4 a = s4[0], b = s4[1];
  u16 r[8] = {f2b(a.x), f2b(a.y), f2b(a.z), f2b(a.w),
              f2b(b.x), f2b(b.y), f2b(b.z), f2b(b.w)};
  *reinterpret_cast<v8s*>(dst + (size_t)seg * 2097152 + (size_t)i * 8) =
      *reinterpret_cast<v8s*>(r);
}

// ---------------- weight transpose + cast: W (K x N) f32 -> Wt (N x K) bf16 ------
__global__ void __launch_bounds__(256) transpose_cast_kernel(const float* __restrict__ W,
                                                             u16* __restrict__ Wt,
                                                             int K, int N) {
  __shared__ float t[32][33];
  int tx = threadIdx.x & 31, ty = threadIdx.x >> 5;
  int kb = blockIdx.y * 32, nb = blockIdx.x * 32;
#pragma unroll
  for (int i = 0; i < 4; i++) {
    int r = ty + i * 8;
    t[r][tx] = W[(size_t)(kb + r) * N + nb + tx];
  }
  __syncthreads();
#pragma unroll
  for (int i = 0; i < 4; i++) {
    int r = ty + i * 8;
    Wt[(size_t)(nb + r) * K + kb + tx] = f2b(t[tx][r]);
  }
}

// ---------------- extract coords (B,S,3) from x_0[..., :3] -----------------------
__global__ void coords_kernel(const float* __restrict__ x0, float* __restrict__ c, int n) {
  int i = blockIdx.x * blockDim.x + threadIdx.x;
  if (i < n) {
    c[i * 3 + 0] = x0[(size_t)i * ND + 0];
    c[i * 3 + 1] = x0[(size_t)i * ND + 1];
    c[i * 3 + 2] = x0[(size_t)i * ND + 2];
  }
}

// ---------------- bf16 MFMA GEMM, C = A(MxK) @ Wt(NxK)^T + bias ------------------
__global__ void __launch_bounds__(256) gemm_kernel(const u16* __restrict__ A,
                                                   const u16* __restrict__ Wt,
                                                   const float* __restrict__ bias,
                                                   u16* __restrict__ outK,
                                                   u16* __restrict__ outV,
                                                   float* __restrict__ outF,
                                                   int M, int N, int K, int mode, int f) {
  __shared__ u16 At[64 * 40];
  __shared__ u16 Bt[64 * 40];
  int nt = N >> 6;
  int by = blockIdx.x / nt, bx = blockIdx.x % nt;
  int tid = threadIdx.x;
  int lane = tid & 63, wave = tid >> 6;
  int g = lane >> 4, li = lane & 15;
  int wm = (wave & 1) * 32, wn = (wave >> 1) * 32;
  f32x4 acc[2][2] = {};
  int sr = tid >> 2, sc = tid & 3;
  const u16* Arow = A + (size_t)(by * 64 + sr) * K + sc * 8;
  const u16* Brow = Wt + (size_t)(bx * 64 + sr) * K + sc * 8;
  for (int kb = 0; kb < K; kb += 32) {
    v8s av = *reinterpret_cast<const v8s*>(Arow + kb);
    v8s bv = *reinterpret_cast<const v8s*>(Brow + kb);
    __syncthreads();
    *reinterpret_cast<v8s*>(&At[sr * 40 + sc * 8]) = av;
    *reinterpret_cast<v8s*>(&Bt[sr * 40 + sc * 8]) = bv;
    __syncthreads();
#pragma unroll
    for (int mi = 0; mi < 2; mi++) {
      v8s a = *reinterpret_cast<v8s*>(&At[(wm + mi * 16 + li) * 40 + g * 8]);
#pragma unroll
      for (int ni = 0; ni < 2; ni++) {
        v8s b = *reinterpret_cast<v8s*>(&Bt[(wn + ni * 16 + li) * 40 + g * 8]);
        acc[mi][ni] = __builtin_amdgcn_mfma_f32_16x16x32_bf16(a, b, acc[mi][ni], 0, 0, 0);
      }
    }
  }
#pragma unroll
  for (int mi = 0; mi < 2; mi++)
#pragma unroll
    for (int ni = 0; ni < 2; ni++)
#pragma unroll
      for (int r = 0; r < 4; r++) {
        int mrow = by * 64 + wm + mi * 16 + 4 * g + r;
        int n = bx * 64 + wn + ni * 16 + li;
        float val = acc[mi][ni][r] + bias[n];
        if (mode == 2) {
          outF[(size_t)mrow * N + n] = val;
        } else {
          int b = mrow >> 10, s = mrow & 1023;
          bool isv = (mode == 1) && (n >= 512);
          float partner = __shfl_xor(val, 1);
          if (!isv) {
            int d = n & 63, h = (n & 511) >> 6;
            int j = d >> 1;
            float freq = __expf(-(float)j * 0.21586735246819178f);
            float ang = (float)(s >> 7) * freq;
            float sn, cs;
            sincosf(ang, &sn, &cs);
            float res = (n & 1) ? (partner * sn + val * cs) : (val * cs - partner * sn);
            size_t idx;
            if (mode == 0)
              idx = ((size_t)(b * NH + h) * NS + s) * NDH + d;
            else
              idx = ((size_t)((f * NB + b) * NH + h) * NS + s) * NDH + d;
            outK[idx] = f2b(res);
          } else {
            int vd = n - 512;
            int h = vd >> 6, d = vd & 63;
            outV[((size_t)((f * NB + b) * NH + h) * NDH + d) * NS + s] = f2b(val);
          }
        }
      }
}

// ---------------- SH-bias MLP 4->16->16->8, writes MFMA-fragment layout ----------
__global__ void __launch_bounds__(256) bias_kernel(const float* __restrict__ coords,
                                                   const float* __restrict__ W1,
                                                   const float* __restrict__ b1,
                                                   const float* __restrict__ W2,
                                                   const float* __restrict__ b2,
                                                   const float* __restrict__ W3,
                                                   const float* __restrict__ b3,
                                                   u16* __restrict__ biasF) {
  __shared__ float w[488];
  int tid = threadIdx.x;
  if (tid < 64) w[tid] = W1[tid];
  if (tid < 16) { w[64 + tid] = b1[tid]; w[336 + tid] = b2[tid]; }
  w[80 + tid] = W2[tid];
  if (tid < 128) w[352 + tid] = W3[tid];
  if (tid < 8) w[480 + tid] = b3[tid];
  __syncthreads();
  int blk = blockIdx.x;
  int kb = blk & 3, q = (blk >> 2) & 1023, b = blk >> 12;
  int kk = kb * 256 + tid;
  float cqx = coords[(size_t)(b * NS + q) * 3 + 0];
  float cqy = coords[(size_t)(b * NS + q) * 3 + 1];
  float cqz = coords[(size_t)(b * NS + q) * 3 + 2];
  float rx = cqx - coords[(size_t)(b * NS + kk) * 3 + 0];
  float ry = cqy - coords[(size_t)(b * NS + kk) * 3 + 1];
  float rz = cqz - coords[(size_t)(b * NS + kk) * 3 + 2];
  float nrm = sqrtf(rx * rx + ry * ry + rz * rz);
  float inv = 1.0f / (nrm + 1e-6f);
  const float Y1 = 0.4886025119029199f;
  const float Y0 = 0.28209479177387814f;
  float shy = Y1 * ry * inv, shz = Y1 * rz * inv, shx = Y1 * rx * inv;
  const f32x4* W1v = reinterpret_cast<const f32x4*>(w);
  const f32x4* b1v = reinterpret_cast<const f32x4*>(w + 64);
  const f32x4* W2v = reinterpret_cast<const f32x4*>(w + 80);
  const f32x4* b2v = reinterpret_cast<const f32x4*>(w + 336);
  const f32x4* W3v = reinterpret_cast<const f32x4*>(w + 352);
  const f32x4* b3v = reinterpret_cast<const f32x4*>(w + 480);
  f32x4 h1v[4], h2v[4];
#pragma unroll
  for (int jv = 0; jv < 4; jv++) {
    f32x4 a = b1v[jv] + Y0 * W1v[jv] + shy * W1v[4 + jv] + shz * W1v[8 + jv] + shx * W1v[12 + jv];
#pragma unroll
    for (int c = 0; c < 4; c++) a[c] = a[c] / (1.0f + __expf(-a[c]));
    h1v[jv] = a;
  }
#pragma unroll
  for (int jv = 0; jv < 4; jv++) {
    f32x4 a = b2v[jv];
#pragma unroll
    for (int i = 0; i < 16; i++) a += h1v[i >> 2][i & 3] * W2v[i * 4 + jv];
#pragma unroll
    for (int c = 0; c < 4; c++) a[c] = a[c] / (1.0f + __expf(-a[c]));
    h2v[jv] = a;
  }
  f32x4 o0 = b3v[0], o1 = b3v[1];
#pragma unroll
  for (int i = 0; i < 16; i++) {
    float hs = h2v[i >> 2][i & 3];
    o0 += hs * W3v[i * 2];
    o1 += hs * W3v[i * 2 + 1];
  }
  int qt = q >> 4, liq = q & 15;
  int kt = kk >> 5, kks = (kk >> 4) & 1, gg = (kk >> 2) & 3, rr = kk & 3;
  const size_t hstride = 1048576;
  size_t slot0 = ((((size_t)(b * NH) * 64 + qt) * 32 + kt) * 64 + gg * 16 + liq) * 8 +
                 kks * 4 + rr;
#pragma unroll
  for (int hh = 0; hh < 4; hh++) {
    biasF[slot0 + (size_t)hh * hstride] = f2b(o0[hh]);
    biasF[slot0 + (size_t)(hh + 4) * hstride] = f2b(o1[hh]);
  }
}

// ---------------- fused flash attention: LDS-staged, 2-phase pipelined -----------
// grid 512 = 32 bh x 16 qb (XCD-chunked); block 256 = 4 waves, wave w: q-rows qb*64+w*16..
// Per 32-key tile: 24KB of K+V (3 feats) staged via global_load_lds into
// FRAGMENT-ORDER LDS (staging does the transpose; all ds_reads lane-linear).
#define ATTN_LDSB 12288  // u16 per buffer (24KB)
__global__ void __launch_bounds__(256, 2) attn_kernel(const u16* __restrict__ q,
                                                      const u16* __restrict__ kmat,
                                                      const u16* __restrict__ vt,
                                                      const u16* __restrict__ biasF,
                                                      const float* __restrict__ fw,
                                                      const float* __restrict__ denom,
                                                      u16* __restrict__ attno) {
  __shared__ u16 sbuf[2 * ATTN_LDSB];
  int d = blockIdx.x;
  int x = d & 7, u = d >> 3;
  int bh = x * 4 + (u & 3);  // 16 blocks per bh share one XCD (round-robin assumption)
  int qb = u >> 2;
  int h = bh & 7, b = bh >> 3;
  int wave = threadIdx.x >> 6, lane = threadIdx.x & 63;
  int g = lane >> 4, li = lane & 15;
  int qt = qb * 4 + wave;

  float f0 = fw[0], f1 = fw[1], f2v = fw[2];
  float mxg = fmaxf(fmaxf(f0, f1), f2v);
  float e0 = __expf(f0 - mxg), e1 = __expf(f1 - mxg), e2 = __expf(f2v - mxg);
  float es = e0 + e1 + e2;
  float gates[3] = {e0 / es, e1 / es, e2 / es};
  float invd = 1.0f / denom[h];

  const u16* qbase = q + ((size_t)bh * NS + qt * 16 + li) * NDH + g * 8;
  v8s qa0 = *reinterpret_cast<const v8s*>(qbase);
  v8s qa1 = *reinterpret_cast<const v8s*>(qbase + 32);
  const u16* bfrag = biasF + (size_t)bh * 1048576 + (size_t)qt * 16384;

  // stage tile kt into buffer p: 24 chunks of 1KB, 6 per wave, fragment-order LDS
  auto stage = [&](int kt, int p) {
    int k0 = kt * 32;
    u16* bufb = sbuf + p * ATTN_LDSB;
#pragma unroll
    for (int j = 0; j < 6; j++) {
      int c = wave + 4 * j;
      if (c < 12) {  // K: chunk (ff, kks, half); lane -> K[k0+kks*16+li][half*32+g*8..]
        int ff = c >> 2, kks = (c >> 1) & 1, half = c & 1;
        const u16* src = kmat + ((size_t)(ff * 32 + bh) * NS + k0 + kks * 16 + li) * NDH +
                         half * 32 + g * 8;
        gl16(src, bufb + ff * 2048 + (c & 3) * 512 + lane * 8);
      } else {  // V: chunk (ff, ni); lane -> V^T[ni*16+li][k0+g*8..]
        int cc = c - 12, ff = cc >> 2, ni = cc & 3;
        const u16* src = vt + ((size_t)(ff * 32 + bh) * NDH + ni * 16 + li) * NS + k0 + g * 8;
        gl16(src, bufb + 6144 + ff * 2048 + ni * 512 + lane * 8);
      }
    }
  };

  float m[3] = {0.f, 0.f, 0.f};
  float lr[3] = {0.f, 0.f, 0.f};
  f32x4 o[3][4] = {};
  f32x4 zero = {0.f, 0.f, 0.f, 0.f};
  int s0lane = ((g & 1) << 5) + li;
  int kksT = g >> 1;

  stage(0, 0);  // prologue: 6 loads in flight per wave

  for (int t = 0; t < 32; t++) {
    int p = t & 1;
    // bias fragment for tile t (drained by the vmcnt below)
    v8s bb = *reinterpret_cast<const v8s*>(bfrag + ((size_t)t * 64 + lane) * 8);
    if (t < 31) {
      stage(t + 1, p ^ 1);  // 6 newest VMEM ops = next tile
      asm volatile("s_waitcnt vmcnt(6)" ::: "memory");  // drain tile t + bias, keep t+1
    } else {
      asm volatile("s_waitcnt vmcnt(0)" ::: "memory");
    }
    __builtin_amdgcn_s_barrier();
    __builtin_amdgcn_sched_barrier(0);  // pin ds_reads below the barrier
    const u16* bufb = sbuf + p * ATTN_LDSB;
#pragma unroll
    for (int ff = 0; ff < 3; ff++) {
      v8s kf[2][2], vb[4];
#pragma unroll
      for (int kks = 0; kks < 2; kks++)
#pragma unroll
        for (int half = 0; half < 2; half++)
          kf[kks][half] = *reinterpret_cast<const v8s*>(
              bufb + ff * 2048 + (kks * 2 + half) * 512 + lane * 8);
#pragma unroll
      for (int ni = 0; ni < 4; ni++)
        vb[ni] = *reinterpret_cast<const v8s*>(bufb + 6144 + ff * 2048 + ni * 512 + lane * 8);
      // swapped QK^T: C lane holds P[k = kks*16+4g+r][q = li]
      float pv[2][4];
#pragma unroll
      for (int kks = 0; kks < 2; kks++) {
        f32x4 sc = __builtin_amdgcn_mfma_f32_16x16x32_bf16(kf[kks][0], qa0, zero, 0, 0, 0);
        sc = __builtin_amdgcn_mfma_f32_16x16x32_bf16(kf[kks][1], qa1, sc, 0, 0, 0);
#pragma unroll
        for (int r = 0; r < 4; r++)
          pv[kks][r] = sc[r] * invd + b2f((u16)bb[kks * 4 + r]);
      }
      float pmax = pv[0][0];
#pragma unroll
      for (int kks = 0; kks < 2; kks++)
#pragma unroll
        for (int r = 0; r < 4; r++) pmax = fmaxf(pmax, pv[kks][r]);
      if (!__all(pmax - m[ff] <= 8.0f)) {  // rare: raise wave-uniform max, rescale
        float rm = pmax;
        rm = fmaxf(rm, __shfl_xor(rm, 1));
        rm = fmaxf(rm, __shfl_xor(rm, 2));
        rm = fmaxf(rm, __shfl_xor(rm, 4));
        rm = fmaxf(rm, __shfl_xor(rm, 8));
        rm = fmaxf(rm, __shfl_xor(rm, 16));
        rm = fmaxf(rm, __shfl_xor(rm, 32));
        float sc2 = __expf(m[ff] - rm);
        lr[ff] *= sc2;
#pragma unroll
        for (int ni = 0; ni < 4; ni++)
#pragma unroll
          for (int r = 0; r < 4; r++) o[ff][ni][r] *= sc2;
        m[ff] = rm;
      }
      float p2[2][4];
#pragma unroll
      for (int kks = 0; kks < 2; kks++)
#pragma unroll
        for (int r = 0; r < 4; r++) {
          p2[kks][r] = __expf(pv[kks][r] - m[ff]);
          lr[ff] += p2[kks][r];
        }
      // in-register P repack -> A-fragment (proven in R3)
      unsigned int ps00 = ((unsigned int)f2b(p2[0][1]) << 16) | f2b(p2[0][0]);
      unsigned int ps01 = ((unsigned int)f2b(p2[0][3]) << 16) | f2b(p2[0][2]);
      unsigned int ps10 = ((unsigned int)f2b(p2[1][1]) << 16) | f2b(p2[1][0]);
      unsigned int ps11 = ((unsigned int)f2b(p2[1][3]) << 16) | f2b(p2[1][2]);
      int a00 = __shfl((int)ps00, s0lane), a01 = __shfl((int)ps01, s0lane);
      int a10 = __shfl((int)ps10, s0lane), a11 = __shfl((int)ps11, s0lane);
      int c00 = __shfl((int)ps00, s0lane + 16), c01 = __shfl((int)ps01, s0lane + 16);
      int c10 = __shfl((int)ps10, s0lane + 16), c11 = __shfl((int)ps11, s0lane + 16);
      int warr[4];
      warr[0] = kksT ? a10 : a00;
      warr[1] = kksT ? a11 : a01;
      warr[2] = kksT ? c10 : c00;
      warr[3] = kksT ? c11 : c01;
      v8s pa = *reinterpret_cast<v8s*>(warr);
#pragma unroll
      for (int ni = 0; ni < 4; ni++)
        o[ff][ni] = __builtin_amdgcn_mfma_f32_16x16x32_bf16(pa, vb[ni], o[ff][ni], 0, 0, 0);
    }
    __builtin_amdgcn_s_barrier();  // WAR: all waves done reading buf[p] before restage
  }
  // epilogue: in-wave only. lane(g,li): o[q=4g+r][d=ni*16+li]; l lives at q=li lanes.
  float out[4][4] = {};
#pragma unroll
  for (int ff = 0; ff < 3; ff++) {
    float l = lr[ff];
    l += __shfl_xor(l, 16);
    l += __shfl_xor(l, 32);
    float scl = gates[ff] / l;
    float srow[4];
#pragma unroll
    for (int r = 0; r < 4; r++)
      srow[r] = __shfl(scl, (lane & 48) | (((lane >> 2) & 12) + r));
#pragma unroll
    for (int ni = 0; ni < 4; ni++)
#pragma unroll
      for (int r = 0; r < 4; r++) out[ni][r] += o[ff][ni][r] * srow[r];
  }
#pragma unroll
  for (int ni = 0; ni < 4; ni++)
#pragma unroll
    for (int r = 0; r < 4; r++)
      attno[((size_t)(b * NS + qt * 16 + 4 * g + r)) * ND + h * NDH + ni * 16 + li] =
          f2b(out[ni][r]);
}

extern "C" void kernel_launch(void* const* d_in, const int* in_sizes, int n_in,
                              void* d_out, int out_size, void* d_ws, size_t ws_size,
                              hipStream_t stream) {
  const float* x0 = (const float*)d_in[0];
  const float* v0 = (const float*)d_in[1];
  const float* cf = (const float*)d_in[2];
  const float* qd = (const float*)d_in[3];
  const float* Wq = (const float*)d_in[4];
  const float* bq = (const float*)d_in[5];
  const float* Wkv = (const float*)d_in[6];
  const float* bkv = (const float*)d_in[7];
  const float* Wo = (const float*)d_in[8];
  const float* bo = (const float*)d_in[9];
  const float* fw = (const float*)d_in[10];
  const float* dnm = (const float*)d_in[11];
  const float* W1 = (const float*)d_in[12];
  const float* b1 = (const float*)d_in[13];
  const float* W2 = (const float*)d_in[14];
  const float* b2 = (const float*)d_in[15];
  const float* W3 = (const float*)d_in[16];
  const float* b3 = (const float*)d_in[17];

  char* ws = (char*)d_ws;
  size_t off = 0;
  auto alloc = [&](size_t bytes) -> void* {
    void* p = ws + off;
    off = (off + bytes + 255) & ~(size_t)255;
    return p;
  };
  const size_t E = 4096ull * 512;
  u16* Aq = (u16*)alloc(E * 2);
  u16* Af = (u16*)alloc(3 * E * 2);  // contiguous after Aq (cast4 relies on this)
  u16* Wqt = (u16*)alloc(262144ull * 2);
  u16* Wkvt = (u16*)alloc(3ull * 524288 * 2);
  u16* Wot = (u16*)alloc(262144ull * 2);
  float* crd = (float*)alloc(4096ull * 3 * 4);
  u16* qr = (u16*)alloc(E * 2);
  u16* kr = (u16*)alloc(3 * E * 2);
  u16* vtr = (u16*)alloc(3 * E * 2);
  u16* biasF = (u16*)alloc(33554432ull * 2);
  u16* attno = (u16*)alloc(E * 2);
  (void)ws_size; (void)in_sizes; (void)n_in; (void)out_size; (void)Af;

  cast4_kernel<<<4096, 256, 0, stream>>>(qd, x0, v0, cf, Aq);
  coords_kernel<<<16, 256, 0, stream>>>(x0, crd, 4096);
  dim3 tg1(16, 16);
  transpose_cast_kernel<<<tg1, 256, 0, stream>>>(Wq, Wqt, 512, 512);
  dim3 tg2(32, 16);
  for (int f = 0; f < 3; f++)
    transpose_cast_kernel<<<tg2, 256, 0, stream>>>(Wkv + (size_t)f * 524288,
                                                   Wkvt + (size_t)f * 524288, 512, 1024);
  transpose_cast_kernel<<<tg1, 256, 0, stream>>>(Wo, Wot, 512, 512);

  gemm_kernel<<<512, 256, 0, stream>>>(Aq, Wqt, bq, qr, nullptr, nullptr,
                                       4096, 512, 512, 0, 0);
  for (int f = 0; f < 3; f++)
    gemm_kernel<<<1024, 256, 0, stream>>>(Af + (size_t)f * E, Wkvt + (size_t)f * 524288,
                                          bkv + f * 1024, kr, vtr, nullptr,
                                          4096, 1024, 512, 1, f);
  bias_kernel<<<16384, 256, 0, stream>>>(crd, W1, b1, W2, b2, W3, b3, biasF);
  attn_kernel<<<512, 256, 0, stream>>>(qr, kr, vtr, biasF, fw, dnm, attno);
  gemm_kernel<<<512, 256, 0, stream>>>(attno, Wot, bo, nullptr, nullptr, (float*)d_out,
                                       4096, 512, 512, 2, 0);
}